// Round 2
// baseline (104.416 us; speedup 1.0000x reference)
//
#include <hip/hip_runtime.h>

#define N        384
#define DIM      256
#define D4       (DIM / 4)       // 64 float4 per row
#define MARGIN_F 0.2f
#define NANCH    2               // anchors per block
#define NBLK     (N / NANCH)     // 192 blocks (<= 256 CUs, all resident)
#define NTHR     384
#define NWAVE    (NTHR / 64)     // 6 waves
#define ROWSPW   (N / NWAVE)     // 64 rows per wave in the GEMV stage
#define MAXPOS   64              // labels ~ Binom(384,1/32): mean 12; 64 is >14 sigma

// ---------------------------------------------------------------------------
// Single fused kernel: no norm pre-pass, no eTv staging buffer, no grid
// barrier. Each block re-derives the distance rows it needs straight from the
// raw row-major embeddings:
//   stage A: waves 0-1 normalize the 2 anchor rows into LDS (exact elementwise
//            v*inv, matching ref), all threads stage labels.
//   stage B: wave w owns rows [w*64, w*64+64). Per row: one coalesced 1KB
//            wave-load of the raw row, 3-value xor-butterfly reduce
//            (||v||^2, v.a0n, v.a1n), then D = sqrt(max(sqa + sqj
//            - 2*(rdot*inv_j), 0)). Normalization folded in analytically.
//   stage C: positive lists + semihard accumulation (unchanged).
//   tail:    r0-style contended atomics on one cacheline (measured faster than
//            r1's per-block slots: the RMW serialization hides under the
//            staggered block completions; slot reads added a latency tail).
// Workspace: 16 bytes (sum, cnt, done) zeroed by a tiny memset.
// ---------------------------------------------------------------------------

__global__ __launch_bounds__(NTHR) void triplet_kernel(
    const float* __restrict__ emb, const int* __restrict__ labels,
    float* __restrict__ accum_sum, unsigned int* __restrict__ accum_cnt,
    unsigned int* __restrict__ done_cnt, float* __restrict__ out)
{
    const int i0   = blockIdx.x * NANCH;
    const int tid  = threadIdx.x;      // 0..383
    const int wave = tid >> 6, lane = tid & 63;

    __shared__ float4 ei4[NANCH][D4];  // normalized anchor rows
    __shared__ float  sqa[NANCH];      // sum(e_norm^2) per anchor (~1.0)
    __shared__ float  Drow[NANCH][N];  // distance rows
    __shared__ int    lab[N];
    __shared__ int    posList[NANCH][MAXPOS];
    __shared__ int    posCnt[NANCH];
    __shared__ float        sredS[NWAVE];
    __shared__ unsigned int sredC[NWAVE];

    // ---- stage A: anchors + labels
    lab[tid] = labels[tid];
    if (tid < NANCH) posCnt[tid] = 0;
    if (wave < NANCH) {                // wave 0 -> anchor 0, wave 1 -> anchor 1
        const float4 v = ((const float4*)emb)[(i0 + wave) * D4 + lane];
        float s = v.x*v.x + v.y*v.y + v.z*v.z + v.w*v.w;
        #pragma unroll
        for (int m = 1; m < 64; m <<= 1) s += __shfl_xor(s, m, 64);
        const float inv = 1.0f / fmaxf(sqrtf(s), 1e-12f);
        float4 vn;
        vn.x = v.x*inv; vn.y = v.y*inv; vn.z = v.z*inv; vn.w = v.w*inv;
        ei4[wave][lane] = vn;          // exact elementwise normalize (= ref)
        if (lane == 0) sqa[wave] = s * inv * inv;
    }
    __syncthreads();

    // ---- stage B: wave-per-row GEMV on raw embeddings (coalesced 1KB/wave)
    const float4 a0 = ei4[0][lane];    // anchor fragments hoisted to registers
    const float4 a1 = ei4[1][lane];
    const float  sq0 = sqa[0], sq1 = sqa[1];
    const float4* __restrict__ embr = (const float4*)emb;
    const int jbase = wave * ROWSPW;

    #pragma unroll 4
    for (int r = 0; r < ROWSPW; ++r) {
        const int j = jbase + r;
        const float4 v = embr[j * D4 + lane];
        float vv  = v.x*v.x  + v.y*v.y  + v.z*v.z  + v.w*v.w;
        float rd0 = v.x*a0.x + v.y*a0.y + v.z*a0.z + v.w*a0.w;
        float rd1 = v.x*a1.x + v.y*a1.y + v.z*a1.z + v.w*a1.w;
        #pragma unroll
        for (int m = 1; m < 64; m <<= 1) {   // 3-value butterfly: all lanes get sums
            vv  += __shfl_xor(vv,  m, 64);
            rd0 += __shfl_xor(rd0, m, 64);
            rd1 += __shfl_xor(rd1, m, 64);
        }
        const float inv = 1.0f / fmaxf(sqrtf(vv), 1e-12f);
        const float sqj = vv * inv * inv;    // = ref's sum(e_norm^2) for row j
        if (lane < NANCH) {                  // lane 0 -> anchor 0, lane 1 -> anchor 1
            const float rd = (lane == 0) ? rd0 : rd1;
            const float sa = (lane == 0) ? sq0 : sq1;
            const float d2 = fmaxf(sa + sqj - 2.0f * (rd * inv), 0.0f);
            Drow[lane][j] = (d2 > 0.0f) ? sqrtf(d2) : 0.0f;
        }
    }
    __syncthreads();

    // ---- stage C1: positive lists for both anchors
    const int lj = lab[tid];
    #pragma unroll
    for (int a = 0; a < NANCH; ++a) {
        const int ia = i0 + a;
        if (lj == lab[ia] && tid != ia)
            posList[a][atomicAdd(&posCnt[a], 1)] = tid;
    }
    __syncthreads();

    // ---- stage C2: semihard accumulation; thread tid owns negative k = tid
    float        lsum = 0.0f;
    unsigned int lcnt = 0u;
    #pragma unroll
    for (int a = 0; a < NANCH; ++a) {
        const int   li = lab[i0 + a];
        const float dk = Drow[a][tid];         // an (if tid is a negative)
        if (lj != li) {
            const int np = posCnt[a];          // ~11 positives
            for (int p = 0; p < np; ++p) {
                const float tm = dk - Drow[a][posList[a][p]];   // an - ap
                if (tm > 0.0f && tm <= MARGIN_F) {
                    const float l = MARGIN_F - tm;              // max(MARGIN-tm,0)
                    lsum += l;
                    if (l > 0.0f) lcnt++;                       // strict losses>0 count
                }
            }
        }
    }

    // ---- block reduce
    #pragma unroll
    for (int off = 32; off > 0; off >>= 1) {
        lsum += __shfl_down(lsum, off, 64);
        lcnt += __shfl_down(lcnt, off, 64);
    }
    if (lane == 0) { sredS[wave] = lsum; sredC[wave] = lcnt; }
    __syncthreads();

    // ---- r0-style tail: contended single-line atomics (hidden under staggered
    //      block completion), last block finalizes with 2 atomic reads
    if (tid == 0) {
        float        S = 0.0f;
        unsigned int C = 0u;
        #pragma unroll
        for (int w = 0; w < NWAVE; ++w) { S += sredS[w]; C += sredC[w]; }
        if (S != 0.0f || C != 0u) {
            atomicAdd(accum_sum, S);
            atomicAdd(accum_cnt, C);
        }
        __threadfence();                        // order adds before done++
        const unsigned int prev = atomicAdd(done_cnt, 1);
        if (prev == NBLK - 1) {                 // last block computes the mean
            const float        Sall = atomicAdd(accum_sum, 0.0f);
            const unsigned int Call = atomicAdd(accum_cnt, 0u);
            out[0] = (Call > 0u) ? (Sall / (float)Call) : 0.0f;
        }
    }
}

extern "C" void kernel_launch(void* const* d_in, const int* in_sizes, int n_in,
                              void* d_out, int out_size, void* d_ws, size_t ws_size,
                              hipStream_t stream) {
    const float* emb    = (const float*)d_in[0];   // (384, 256) fp32
    const int*   labels = (const int*)d_in[1];     // (384,) int32
    float*       out    = (float*)d_out;           // scalar fp32

    float*        accum_sum = (float*)d_ws;                    // [0]
    unsigned int* accum_cnt = (unsigned int*)accum_sum + 1;    // [1]
    unsigned int* done_cnt  = (unsigned int*)accum_sum + 2;    // [2]

    hipMemsetAsync(d_ws, 0, 16, stream);           // zero sum/cnt/done (graph-legal)
    triplet_kernel<<<NBLK, NTHR, 0, stream>>>(emb, labels,
                                              accum_sum, accum_cnt, done_cnt, out);
}

// Round 3
// 74.737 us; speedup vs baseline: 1.3971x; 1.3971x over previous
//
#include <hip/hip_runtime.h>

#define N        384
#define DIM      256
#define D4       (DIM / 4)       // 64 float4 per row
#define KH       (D4 / 2)        // 32 float4 per k-half
#define MARGIN_F 0.2f
#define NANCH    2               // anchors per fused block
#define NBLK     (N / NANCH)     // 192 blocks
#define NTHR     (2 * N)         // 768 threads: split-K x2 over 384 columns
#define NWAVE    (NTHR / 64)     // 12 waves
#define MAXPOS   64              // labels ~ Binom(384,1/32): mean 12; 64 is >14 sigma

// ---------------------------------------------------------------------------
// r0 structure (norm pre-pass -> eTv k4-major -> thread-per-column fused),
// which measured 77.4us, plus split-K x2 in the fused kernel:
//   threads [0,N)    : columns, k4 in [0,32)
//   threads [N,2N)   : same columns, k4 in [32,64)  -> partials via LDS
// Halves the serial load chain (32 loads vs 64) and doubles waves/SIMD
// (1.5 -> 3) for latency hiding. Stage-C negatives split too: each k-group
// owns one anchor. r2's shuffle-GEMV is reverted (52us kernel, latency-bound
// on 18-step cross-lane chains).
//
// Workspace layout:
//   [0..15]   accum: sum(float), cnt(uint), done(uint) — zeroed by 16B memset
//   [16..]    eTv : N*DIM floats as float4[k4][j]  (k4-major, j fastest)
//   then      sqn : N floats, sum(e_norm^2) per row (~1.0; ref recomputes it)
// ---------------------------------------------------------------------------

__global__ __launch_bounds__(64) void norm_kernel(
    const float* __restrict__ emb, float4* __restrict__ eTv,
    float* __restrict__ sqn)
{
    const int row  = blockIdx.x;       // 0..N-1
    const int lane = threadIdx.x;      // 0..63, one float4 each = whole row

    const float4 v = ((const float4*)emb)[row * D4 + lane];   // coalesced 1KB/wave
    float s = v.x*v.x + v.y*v.y + v.z*v.z + v.w*v.w;
    #pragma unroll
    for (int off = 32; off > 0; off >>= 1) s += __shfl_down(s, off, 64);
    const float tot = __shfl(s, 0, 64);                       // broadcast

    const float inv = 1.0f / fmaxf(sqrtf(tot), 1e-12f);
    float4 vn;
    vn.x = v.x * inv; vn.y = v.y * inv; vn.z = v.z * inv; vn.w = v.w * inv;
    eTv[lane * N + row] = vn;          // transposed-float4 store (posted, async)

    if (lane == 0) sqn[row] = tot * inv * inv;   // matches ref's recompute on e_norm
}

__global__ __launch_bounds__(NTHR) void fused_kernel(
    const float4* __restrict__ eTv, const float* __restrict__ sqn,
    const int* __restrict__ labels,
    float* __restrict__ accum_sum, unsigned int* __restrict__ accum_cnt,
    unsigned int* __restrict__ done_cnt, float* __restrict__ out)
{
    const int i0   = blockIdx.x * NANCH;
    const int tid  = threadIdx.x;      // 0..767
    const int wave = tid >> 6, lane = tid & 63;
    const int kgrp = (tid >= N) ? 1 : 0;   // which k-half this thread sums
    const int col  = tid - kgrp * N;       // 0..383: column owned

    __shared__ float4 ei4[NANCH][D4];  // normalized anchor rows
    __shared__ float  sqa[NANCH];
    __shared__ float  pacc[NANCH][N];  // k-high partial dots
    __shared__ float  Drow[NANCH][N];  // distance rows (never touch global)
    __shared__ int    lab[N];
    __shared__ int    posList[NANCH][MAXPOS];
    __shared__ int    posCnt[NANCH];
    __shared__ float        sredS[NWAVE];
    __shared__ unsigned int sredC[NWAVE];

    // stage anchors (already normalized in eTv) + labels
    if (tid < NANCH * D4) {            // 128 threads: a = tid/64, k4 = tid%64
        const int a = tid >> 6, k4 = tid & (D4 - 1);
        ei4[a][k4] = eTv[k4 * N + (i0 + a)];
    }
    if (tid < NANCH) { sqa[tid] = sqn[i0 + tid]; posCnt[tid] = 0; }
    if (tid < N) lab[tid] = labels[tid];
    __syncthreads();

    // ---- distance rows, split-K: thread owns (col, k-half); 32 coalesced loads
    float acc0 = 0.0f, acc1 = 0.0f;
    const int kbase = kgrp * KH;
    #pragma unroll 8
    for (int k = 0; k < KH; ++k) {
        const int k4 = kbase + k;
        const float4 v  = eTv[k4 * N + col];   // global_load_dwordx4, 8 in flight
        const float4 a0 = ei4[0][k4];          // ds_read_b128 broadcast (free)
        const float4 a1 = ei4[1][k4];
        acc0 += v.x*a0.x + v.y*a0.y + v.z*a0.z + v.w*a0.w;
        acc1 += v.x*a1.x + v.y*a1.y + v.z*a1.z + v.w*a1.w;
    }
    if (kgrp == 1) { pacc[0][col] = acc0; pacc[1][col] = acc1; }
    __syncthreads();

    if (kgrp == 0) {                   // combine halves, finalize distances
        acc0 += pacc[0][col];
        acc1 += pacc[1][col];
        const float sqj = sqn[col];
        float d2 = fmaxf(sqa[0] + sqj - 2.0f * acc0, 0.0f);
        Drow[0][col] = (d2 > 0.0f) ? sqrtf(d2) : 0.0f;   // ref: sqrt(where(pos,d2,1))*pos
        d2       = fmaxf(sqa[1] + sqj - 2.0f * acc1, 0.0f);
        Drow[1][col] = (d2 > 0.0f) ? sqrtf(d2) : 0.0f;
    } else {                           // meanwhile: positive lists (labels-only dep)
        const int lj = lab[col];
        #pragma unroll
        for (int a = 0; a < NANCH; ++a) {
            const int ia = i0 + a;
            if (lj == lab[ia] && col != ia)
                posList[a][atomicAdd(&posCnt[a], 1)] = col;
        }
    }
    __syncthreads();

    // ---- semihard accumulation; thread owns (negative = col, anchor = kgrp)
    float        lsum = 0.0f;
    unsigned int lcnt = 0u;
    {
        const int   a  = kgrp;
        const int   li = lab[i0 + a];
        if (lab[col] != li) {
            const float dk = Drow[a][col];     // an
            const int   np = posCnt[a];        // ~11 positives
            for (int p = 0; p < np; ++p) {
                const float tm = dk - Drow[a][posList[a][p]];   // an - ap
                if (tm > 0.0f && tm <= MARGIN_F) {
                    const float l = MARGIN_F - tm;              // max(MARGIN-tm,0)
                    lsum += l;
                    if (l > 0.0f) lcnt++;                       // strict losses>0 count
                }
            }
        }
    }

    // ---- block reduce, device accumulate, last-block finalize
    #pragma unroll
    for (int off = 32; off > 0; off >>= 1) {
        lsum += __shfl_down(lsum, off, 64);
        lcnt += __shfl_down(lcnt, off, 64);
    }
    if (lane == 0) { sredS[wave] = lsum; sredC[wave] = lcnt; }
    __syncthreads();

    if (tid == 0) {
        float        S = 0.0f;
        unsigned int C = 0u;
        #pragma unroll
        for (int w = 0; w < NWAVE; ++w) { S += sredS[w]; C += sredC[w]; }
        if (S != 0.0f || C != 0u) {
            atomicAdd(accum_sum, S);
            atomicAdd(accum_cnt, C);
        }
        __threadfence();                        // order adds before done++
        const unsigned int prev = atomicAdd(done_cnt, 1);
        if (prev == NBLK - 1) {                 // last block computes the mean
            const float        Sall = atomicAdd(accum_sum, 0.0f);
            const unsigned int Call = atomicAdd(accum_cnt, 0u);
            out[0] = (Call > 0u) ? (Sall / (float)Call) : 0.0f;
        }
    }
}

extern "C" void kernel_launch(void* const* d_in, const int* in_sizes, int n_in,
                              void* d_out, int out_size, void* d_ws, size_t ws_size,
                              hipStream_t stream) {
    const float* emb    = (const float*)d_in[0];   // (384, 256) fp32
    const int*   labels = (const int*)d_in[1];     // (384,) int32
    float*       out    = (float*)d_out;           // scalar fp32

    float*        accum_sum = (float*)d_ws;                    // [0]
    unsigned int* accum_cnt = (unsigned int*)accum_sum + 1;    // [1]
    unsigned int* done_cnt  = (unsigned int*)accum_sum + 2;    // [2]
    float4*       eTv = (float4*)((char*)d_ws + 16);           // N*DIM floats
    float*        sqn = (float*)((char*)d_ws + 16 + (size_t)N * DIM * 4);

    hipMemsetAsync(d_ws, 0, 16, stream);           // zero sum/cnt/done (graph-legal)
    norm_kernel<<<N, 64, 0, stream>>>(emb, eTv, sqn);
    fused_kernel<<<NBLK, NTHR, 0, stream>>>(eTv, sqn, labels,
                                            accum_sum, accum_cnt, done_cnt, out);
}

// Round 4
// 72.530 us; speedup vs baseline: 1.4396x; 1.0304x over previous
//
#include <hip/hip_runtime.h>

#define N        384
#define DIM      256
#define D4       (DIM / 4)       // 64 float4 per row
#define CHUNK_K4 8               // k4 staged per chunk
#define NCHUNK   4               // chunks per k-half: 4*8 = 32 k4 = half of D4
#define MARGIN_F 0.2f
#define NANCH    2               // anchors per block
#define NBLK     (N / NANCH)     // 192 blocks
#define NTHR     (2 * N)         // 768 threads: split-K x2 over 384 columns
#define NWAVE    (NTHR / 64)     // 12 waves
#define MAXPOS   64              // labels ~ Binom(384,1/32): mean 12; >14 sigma
#define LROW     (CHUNK_K4 + 1)  // padded LDS row stride in float4 (bank floor)

// ---------------------------------------------------------------------------
// Single compute kernel (plus the 16B memset): no norm pre-pass, no eTv
// transpose buffer (r3's norm_kernel stored 64 scattered 16B lines per wave
// and fused re-read 73MB of it; both gone), one fewer launch boundary.
//
//   stage/dot: kgrp g owns k4 in [g*32, g*32+32), staged in 4 chunks of 8 k4
//              (48KB, coalesced 128B runs from L2 — every block reads the same
//              384KB so it is LLC/L2-hot). Thread-per-column reads its column
//              (padded stride -> bank floor) + 2 anchor rows (broadcast, free)
//              and accumulates vv, rd0, rd1 IN-LANE (no shuffles — r2 lesson).
//   combine:   kgrp1 -> pacc, kgrp0 adds, computes inv_j/sq_j analytically
//              (dot_norm = rd*inv_i*inv_j; r2 validated analytic-inv numerics,
//              distance error ~1e-7). kgrp1 builds positive lists meanwhile.
//   stage C:   thread owns (negative=col, anchor=kgrp); unchanged from r3.
//   tail:      r0 contended single-line atomics + last-block finalize.
// ---------------------------------------------------------------------------

__global__ __launch_bounds__(NTHR) void triplet_kernel(
    const float4* __restrict__ emb4, const int* __restrict__ labels,
    float* __restrict__ accum_sum, unsigned int* __restrict__ accum_cnt,
    unsigned int* __restrict__ done_cnt, float* __restrict__ out)
{
    const int i0   = blockIdx.x * NANCH;
    const int tid  = threadIdx.x;          // 0..767
    const int wave = tid >> 6, lane = tid & 63;
    const int kgrp = (tid >= N) ? 1 : 0;   // which k-half this thread sums
    const int col  = tid - kgrp * N;       // 0..383: column owned

    __shared__ float4 ebuf[2][N][LROW];    // 110.6 KB: one chunk per kgrp
    __shared__ float  pacc[3][N];          // vv, rd0, rd1 partials from kgrp1
    __shared__ float  Drow[NANCH][N];      // distance rows
    __shared__ float  invA[NANCH], sqA[NANCH];
    __shared__ int    lab[N];
    __shared__ int    posList[NANCH][MAXPOS];
    __shared__ int    posCnt[NANCH];
    __shared__ float        sredS[NWAVE];
    __shared__ unsigned int sredC[NWAVE];

    if (tid < N) lab[tid] = labels[tid];
    if (tid < NANCH) posCnt[tid] = 0;

    // ---- staged dot loop: 32 coalesced global loads + 4x(write|read) chunks
    float vv = 0.0f, rd0 = 0.0f, rd1 = 0.0f;
    const int kbase = kgrp * (NCHUNK * CHUNK_K4);    // 0 or 32

    for (int c = 0; c < NCHUNK; ++c) {
        const int kk0 = kbase + c * CHUNK_K4;
        #pragma unroll
        for (int i = 0; i < 8; ++i) {       // 8 float4/thread, 128B runs/8 lanes
            const int s   = i * N + col;    // 0..3071
            const int row = s >> 3, j = s & 7;
            ebuf[kgrp][row][j] = emb4[row * D4 + kk0 + j];
        }
        __syncthreads();
        #pragma unroll
        for (int j = 0; j < CHUNK_K4; ++j) {
            const float4 v  = ebuf[kgrp][col][j];      // bank-floor column read
            const float4 a0 = ebuf[kgrp][i0][j];       // broadcast (free)
            const float4 a1 = ebuf[kgrp][i0 + 1][j];
            vv  += v.x*v.x  + v.y*v.y  + v.z*v.z  + v.w*v.w;
            rd0 += v.x*a0.x + v.y*a0.y + v.z*a0.z + v.w*a0.w;
            rd1 += v.x*a1.x + v.y*a1.y + v.z*a1.z + v.w*a1.w;
        }
        __syncthreads();
    }

    // ---- combine k-halves, publish anchor inv/sq; kgrp1 builds pos lists
    if (kgrp == 1) { pacc[0][col] = vv; pacc[1][col] = rd0; pacc[2][col] = rd1; }
    __syncthreads();

    float inv_j = 0.0f, sq_j = 0.0f;
    if (kgrp == 0) {
        vv  += pacc[0][col];
        rd0 += pacc[1][col];
        rd1 += pacc[2][col];
        inv_j = 1.0f / fmaxf(sqrtf(vv), 1e-12f);
        sq_j  = vv * inv_j * inv_j;         // = ref's sum(e_norm^2) for row j
        if (col == i0)     { invA[0] = inv_j; sqA[0] = sq_j; }
        if (col == i0 + 1) { invA[1] = inv_j; sqA[1] = sq_j; }
    } else {
        const int lj = lab[col];
        #pragma unroll
        for (int a = 0; a < NANCH; ++a) {
            const int ia = i0 + a;
            if (lj == lab[ia] && col != ia)
                posList[a][atomicAdd(&posCnt[a], 1)] = col;
        }
    }
    __syncthreads();

    if (kgrp == 0) {                        // finalize distance rows
        float d2 = fmaxf(sqA[0] + sq_j - 2.0f * (rd0 * (invA[0] * inv_j)), 0.0f);
        Drow[0][col] = (d2 > 0.0f) ? sqrtf(d2) : 0.0f;  // ref: sqrt(where(pos,d2,1))*pos
        d2       = fmaxf(sqA[1] + sq_j - 2.0f * (rd1 * (invA[1] * inv_j)), 0.0f);
        Drow[1][col] = (d2 > 0.0f) ? sqrtf(d2) : 0.0f;
    }
    __syncthreads();

    // ---- semihard accumulation; thread owns (negative = col, anchor = kgrp)
    float        lsum = 0.0f;
    unsigned int lcnt = 0u;
    {
        const int a  = kgrp;
        const int li = lab[i0 + a];
        if (lab[col] != li) {
            const float dk = Drow[a][col];     // an
            const int   np = posCnt[a];        // ~11 positives
            for (int p = 0; p < np; ++p) {
                const float tm = dk - Drow[a][posList[a][p]];   // an - ap
                if (tm > 0.0f && tm <= MARGIN_F) {
                    const float l = MARGIN_F - tm;              // max(MARGIN-tm,0)
                    lsum += l;
                    if (l > 0.0f) lcnt++;                       // strict losses>0
                }
            }
        }
    }

    // ---- block reduce, device accumulate, last-block finalize
    #pragma unroll
    for (int off = 32; off > 0; off >>= 1) {
        lsum += __shfl_down(lsum, off, 64);
        lcnt += __shfl_down(lcnt, off, 64);
    }
    if (lane == 0) { sredS[wave] = lsum; sredC[wave] = lcnt; }
    __syncthreads();

    if (tid == 0) {
        float        S = 0.0f;
        unsigned int C = 0u;
        #pragma unroll
        for (int w = 0; w < NWAVE; ++w) { S += sredS[w]; C += sredC[w]; }
        if (S != 0.0f || C != 0u) {
            atomicAdd(accum_sum, S);
            atomicAdd(accum_cnt, C);
        }
        __threadfence();                        // order adds before done++
        const unsigned int prev = atomicAdd(done_cnt, 1);
        if (prev == NBLK - 1) {                 // last block computes the mean
            const float        Sall = atomicAdd(accum_sum, 0.0f);
            const unsigned int Call = atomicAdd(accum_cnt, 0u);
            out[0] = (Call > 0u) ? (Sall / (float)Call) : 0.0f;
        }
    }
}

extern "C" void kernel_launch(void* const* d_in, const int* in_sizes, int n_in,
                              void* d_out, int out_size, void* d_ws, size_t ws_size,
                              hipStream_t stream) {
    const float4* emb4   = (const float4*)d_in[0];   // (384, 256) fp32
    const int*    labels = (const int*)d_in[1];      // (384,) int32
    float*        out    = (float*)d_out;            // scalar fp32

    float*        accum_sum = (float*)d_ws;                    // [0]
    unsigned int* accum_cnt = (unsigned int*)accum_sum + 1;    // [1]
    unsigned int* done_cnt  = (unsigned int*)accum_sum + 2;    // [2]

    hipMemsetAsync(d_ws, 0, 16, stream);           // zero sum/cnt/done (graph-legal)
    triplet_kernel<<<NBLK, NTHR, 0, stream>>>(emb4, labels,
                                              accum_sum, accum_cnt, done_cnt, out);
}